// Round 6
// baseline (249.302 us; speedup 1.0000x reference)
//
#include <hip/hip_runtime.h>

// SSIM-like loss, factored form:
//   term_n uses 3^n * (ZrV)^(n+1) (ZcH)^(n+1) (channel_sum): ONE vertical and ONE
//   horizontal (2h+1)-tap conv with exact edge-clipped weight rows (in-kernel
//   recurrence). Fixed 80x48 window; H-pass in place in buf. fp32 moment partials,
//   fp64 from wave reduction onward.
//   Accumulation: ZERO atomics. Each block owns a private 64B slot in ws
//   (plain stores); final kernel reduces 4096x5 partials in one block.

typedef float v2f __attribute__((ext_vector_type(2)));
typedef float v4f __attribute__((ext_vector_type(4)));
typedef double v2d __attribute__((ext_vector_type(2)));

#define BSTR 50     // buf float2 stride (even -> 16B-aligned rows for b128)

#define PC 0.19487473f
#define QC 0.23021731f

struct SharedMem {
  v2f buf[80 * BSTR];   // 32,000 B  input window -> H output (in place)
  float Wt[9 * 17];     //    612 B  clipped weight rows
  double wred[4 * 5];   //    160 B  per-wave partials (total ~32.8 KB -> 4 blk/CU)
};

template <int H>
__device__ __forceinline__ void body(SharedMem& sm, int oy, int ox, int tr, int tc,
                                     const float* __restrict__ xp,
                                     const float* __restrict__ yp,
                                     double* __restrict__ slotp) {
  constexpr int T = 2 * H + 1;
  constexpr int n = H - 1;
  constexpr int R0 = 8 - H, R1 = 71 + H;            // used window rows
  const int tid = threadIdx.x;

  // ---- exact clipped 1-D weight rows: Wt[d][k], input offset k-H;
  //      d = dist to edge (0..H-1), d = H = interior row.
  if (tid <= H) {
    float* Wd = sm.Wt + tid * T;
    for (int k = 0; k < T; ++k) Wd[k] = (k == H) ? 1.f : 0.f;
    const int kmin = H - tid;
    for (int m = 0; m < H; ++m) {
      float prev = 0.f;
      for (int k = kmin; k < T; ++k) {
        const float cur = Wd[k];
        const float nxt = (k < T - 1) ? Wd[k + 1] : 0.f;
        Wd[k] = QC * cur + PC * (prev + nxt);
        prev = cur;
      }
    }
  }

  // ---- load: window row r <-> gy=oy+r-8, col cell w <-> gx=ox+w-8; zeros outside ----
  {
    constexpr int CC0 = (8 - H) >> 2, CC1 = (39 + H) >> 2;   // used 4-cell chunks
    const size_t base = (size_t)n * 3145728u;
    for (int c = tid; c < 960; c += 256) {
      const int row = c / 12;
      const int c4 = c - row * 12;
      if (row < R0 || row > R1 || c4 < CC0 || c4 > CC1) continue;
      const int gy = oy + row - 8;
      const int gx0 = ox + c4 * 4 - 8;
      v4f sx = {0.f, 0.f, 0.f, 0.f}, sy = {0.f, 0.f, 0.f, 0.f};
      if (((unsigned)gy < 1024u) && ((unsigned)gx0 < 1024u)) {
        const size_t off = base + (size_t)gy * 1024u + (unsigned)gx0;
        const v4f* px = (const v4f*)(xp + off);
        const v4f* py = (const v4f*)(yp + off);
        sx = px[0] + px[262144] + px[524288];      // 3-channel sum
        sy = py[0] + py[262144] + py[524288];
      }
      v4f* d = (v4f*)(sm.buf + row * BSTR + c4 * 4);
      d[0] = (v4f){sx.x, sy.x, sx.y, sy.y};
      d[1] = (v4f){sx.z, sy.z, sx.w, sy.w};
    }
  }
  __syncthreads();

  // ---- H pass IN PLACE: all reads -> registers, sync, write back ----
  {
    const int g = tid >> 6;              // col-group 0..3 (wave-uniform)
    const int i0 = tid & 63;
    constexpr int I0 = (8 - H) >> 1, I1 = (15 + H) >> 1;   // b128 read range
    const bool colEdge = (tc == 0) | (tc == 31);
    float cw[T];
    int A0[8], sg[8];
    if (colEdge) {
#pragma unroll
      for (int j = 0; j < 8; ++j) {
        const int gx = ox + g * 8 + j;
        int dd = H, rv = 0;
        if (gx < H) dd = gx;
        else if (gx > 1023 - H) { dd = 1023 - gx; rv = 1; }
        A0[j] = dd * T + (rv ? 2 * H : 0);
        sg[j] = rv ? -1 : 1;
      }
    } else {
#pragma unroll
      for (int k = 0; k < T; ++k) cw[k] = sm.Wt[H * T + k];
    }

    auto htask = [&](v2f* o, int r) {
      const v4f* s4 = (const v4f*)(sm.buf + r * BSTR + g * 8);
      v2f win[24];
#pragma unroll
      for (int i = I0; i <= I1; ++i) {
        const v4f t = s4[i];
        win[2 * i] = (v2f){t.x, t.y};
        win[2 * i + 1] = (v2f){t.z, t.w};
      }
      if (!colEdge) {
#pragma unroll
        for (int k = 0; k < T; ++k)
#pragma unroll
          for (int j = 0; j < 8; ++j)
            o[j] += cw[k] * win[j + k + 8 - H];
      } else {
#pragma unroll
        for (int j = 0; j < 8; ++j)
          for (int k = 0; k < T; ++k)
            o[j] += sm.Wt[A0[j] + sg[j] * k] * win[j + k + 8 - H];
      }
    };

    v2f o1[8] = {}, o2[8] = {};
    const int r2 = i0 + 64;
    const bool val1 = (i0 >= R0);
    const bool val2 = (r2 <= R1);
    if (val1) htask(o1, i0);
    if (val2) htask(o2, r2);
    __syncthreads();                       // all reads done before any write
    if (val1) {
      v4f* d = (v4f*)(sm.buf + i0 * BSTR + g * 8 + 8);
#pragma unroll
      for (int jj = 0; jj < 4; ++jj)
        d[jj] = (v4f){o1[2 * jj].x, o1[2 * jj].y, o1[2 * jj + 1].x, o1[2 * jj + 1].y};
    }
    if (val2) {
      v4f* d = (v4f*)(sm.buf + r2 * BSTR + g * 8 + 8);
#pragma unroll
      for (int jj = 0; jj < 4; ++jj)
        d[jj] = (v4f){o2[2 * jj].x, o2[2 * jj].y, o2[2 * jj + 1].x, o2[2 * jj + 1].y};
    }
  }
  __syncthreads();

  // ---- V pass + fp32 moments: 8 contiguous rows/thread from register window ----
  constexpr float scales[8] = {1.f, 3.f, 9.f, 27.f, 81.f, 243.f, 729.f, 2187.f};
  const float scale = scales[n];
  float sA = 0.f, sB = 0.f, sAA = 0.f, sBB = 0.f, sAB = 0.f;
  {
    const int jt = tid & 31;
    const int iv = tid >> 5;             // 0..7
    constexpr int C0 = 8 - H, C1 = 15 + H;
    v2f vwin[24];
#pragma unroll
    for (int c = C0; c <= C1; ++c)
      vwin[c] = sm.buf[(8 * iv + c) * BSTR + 8 + jt];
    v2f o[8] = {};
    const bool rowEdge = (tr == 0) | (tr == 15);
    if (!rowEdge) {
      float cw2[T];
#pragma unroll
      for (int k = 0; k < T; ++k) cw2[k] = sm.Wt[H * T + k];
#pragma unroll
      for (int k = 0; k < T; ++k)
#pragma unroll
        for (int rr = 0; rr < 8; ++rr)
          o[rr] += cw2[k] * vwin[rr + k + 8 - H];
    } else {
#pragma unroll
      for (int rr = 0; rr < 8; ++rr) {
        const int gy = oy + 8 * iv + rr;
        int dd = H, rv = 0;
        if (gy < H) dd = gy;
        else if (gy > 1023 - H) { dd = 1023 - gy; rv = 1; }
        const int A0 = dd * T + (rv ? 2 * H : 0);
        const int s = rv ? -1 : 1;
        for (int k = 0; k < T; ++k)
          o[rr] += sm.Wt[A0 + s * k] * vwin[rr + k + 8 - H];
      }
    }
#pragma unroll
    for (int rr = 0; rr < 8; ++rr) {
      const float A = scale * o[rr].x;
      const float B = scale * o[rr].y;
      sA += A; sB += B;
      sAA += A * A; sBB += B * B; sAB += A * B;
    }
  }

  // ---- wave shfl reduction -> 4 wave partials -> plain 40B store (NO atomics) ----
  double v[5] = {(double)sA, (double)sB, (double)sAA, (double)sBB, (double)sAB};
#pragma unroll
  for (int off = 32; off > 0; off >>= 1) {
#pragma unroll
    for (int k = 0; k < 5; ++k) v[k] += __shfl_down(v[k], off, 64);
  }
  const int lane = tid & 63, wv = tid >> 6;
  if (lane == 0) {
#pragma unroll
    for (int k = 0; k < 5; ++k) sm.wred[wv * 5 + k] = v[k];
  }
  __syncthreads();
  if (tid == 0) {
    double s[5];
#pragma unroll
    for (int k = 0; k < 5; ++k)
      s[k] = sm.wred[k] + sm.wred[5 + k] + sm.wred[10 + k] + sm.wred[15 + k];
    *(v2d*)(slotp)     = (v2d){s[0], s[1]};
    *(v2d*)(slotp + 2) = (v2d){s[2], s[3]};
    slotp[4] = s[4];
  }
}

__global__ __launch_bounds__(256, 4) void ssim_main(const float* __restrict__ xp,
                                                    const float* __restrict__ yp,
                                                    double* __restrict__ acc) {
  __shared__ SharedMem sm;
  const int bid = blockIdx.x;
  const int n = bid & 7;            // sample (interleaved for CU load balance)
  const int tile = bid >> 3;
  const int tc = tile & 31;
  const int tr = tile >> 5;
  const int oy = tr * 64;
  const int ox = tc * 32;
  double* slotp = acc + (size_t)bid * 8;   // private 64B-aligned slot per block
  switch (n) {
    case 0: body<1>(sm, oy, ox, tr, tc, xp, yp, slotp); break;
    case 1: body<2>(sm, oy, ox, tr, tc, xp, yp, slotp); break;
    case 2: body<3>(sm, oy, ox, tr, tc, xp, yp, slotp); break;
    case 3: body<4>(sm, oy, ox, tr, tc, xp, yp, slotp); break;
    case 4: body<5>(sm, oy, ox, tr, tc, xp, yp, slotp); break;
    case 5: body<6>(sm, oy, ox, tr, tc, xp, yp, slotp); break;
    case 6: body<7>(sm, oy, ox, tr, tc, xp, yp, slotp); break;
    default: body<8>(sm, oy, ox, tr, tc, xp, yp, slotp); break;
  }
}

__global__ __launch_bounds__(256) void ssim_final(const double* __restrict__ acc,
                                                  float* __restrict__ out) {
  // One block: 8 samples x 32 lanes; lane l of sample s sums 16 block slots
  // (blocks with bid = s + 8*(l + 32*j), j<16).
  __shared__ double terms[8];
  const int tid = threadIdx.x;
  const int s = tid >> 5;
  const int l = tid & 31;
  double v[5] = {0, 0, 0, 0, 0};
#pragma unroll
  for (int j = 0; j < 16; ++j) {
    const double* p = acc + (size_t)(s + 8 * (l + 32 * j)) * 8;
#pragma unroll
    for (int k = 0; k < 5; ++k) v[k] += p[k];
  }
#pragma unroll
  for (int off = 16; off > 0; off >>= 1) {
#pragma unroll
    for (int k = 0; k < 5; ++k) v[k] += __shfl_down(v[k], off, 32);
  }
  if (l == 0) {
    const double C1 = 6.5025;     // (0.01*255)^2
    const double C2 = 58.5225;    // (0.03*255)^2
    const double N = 1048576.0;
    const double mA = v[0] / N, mB = v[1] / N;
    const double varA = (v[2] - N * mA * mA) / (N - 1.0);
    const double varB = (v[3] - N * mB * mB) / (N - 1.0);
    const double cov  = (v[4] - N * mA * mB) / (N - 1.0);
    terms[s] = ((2.0 * mA * mB + C1) * (2.0 * cov + C2)) /
               ((mA * mA + mB * mB + C1) * (varA * varA + varB * varB + C2));
  }
  __syncthreads();
  if (tid == 0) {
    double tot = 0.0;
    for (int i = 0; i < 8; ++i) tot += terms[i];
    out[0] = (float)tot;
  }
}

extern "C" void kernel_launch(void* const* d_in, const int* in_sizes, int n_in,
                              void* d_out, int out_size, void* d_ws, size_t ws_size,
                              hipStream_t stream) {
  const float* x = (const float*)d_in[0];
  const float* y = (const float*)d_in[1];
  double* acc = (double*)d_ws;           // 4096 * 8 doubles = 256 KB, all rewritten
  float* out = (float*)d_out;

  ssim_main<<<4096, 256, 0, stream>>>(x, y, acc);
  ssim_final<<<1, 256, 0, stream>>>(acc, out);
}